// Round 10
// baseline (541.389 us; speedup 1.0000x reference)
//
#include <hip/hip_runtime.h>

// ---------------- types ----------------
typedef __attribute__((ext_vector_type(8))) short short8;
typedef __attribute__((ext_vector_type(4))) float f32x4;
typedef __attribute__((ext_vector_type(4))) unsigned short u16x4;
typedef unsigned int u32;
typedef unsigned short ushort_t;

union frag_u { u32 w[4]; short8 s; };

static __device__ __forceinline__ unsigned short f2bf(float x) {
  union { float f; unsigned u; } v; v.f = x;
  unsigned r = v.u + 0x7fffu + ((v.u >> 16) & 1u);   // round-to-nearest-even
  return (unsigned short)(r >> 16);
}
static __device__ __forceinline__ float bf2f(unsigned short h) {
  union { unsigned u; float f; } v; v.u = ((unsigned)h) << 16;
  return v.f;
}
static __device__ __forceinline__ u32 pk_bf16(float a, float b) {
  u32 r;
  asm("v_cvt_pk_bf16_f32 %0, %1, %2" : "=v"(r) : "v"(a), "v"(b));
  return r;
}

// LDS-only barrier: lgkmcnt drain, NO vmcnt drain (T4)
static __device__ __forceinline__ void barrier_lds() {
  __builtin_amdgcn_sched_barrier(0);
  asm volatile("s_waitcnt lgkmcnt(0)" ::: "memory");
  __builtin_amdgcn_s_barrier();
  __builtin_amdgcn_sched_barrier(0);
}

// async global->LDS, 16B per lane (linear LDS dest = wave base + lane*16)
static __device__ __forceinline__ void gl_lds16(const void* g, void* s) {
  __builtin_amdgcn_global_load_lds(
      (const __attribute__((address_space(1))) void*)g,
      (__attribute__((address_space(3))) void*)s, 16, 0, 0);
}

// ---------------- fp32 -> bf16, three contiguous regions ----------------
__global__ __launch_bounds__(256) void to_bf16_3(const float* __restrict__ s0,
                                                 const float* __restrict__ s1,
                                                 const float* __restrict__ s2,
                                                 ushort_t* __restrict__ dst,
                                                 int lg2, int n4) {
  int i = blockIdx.x * blockDim.x + threadIdx.x;
  int stride = gridDim.x * blockDim.x;
  for (; i < n4; i += stride) {
    int which = i >> lg2;
    const float* s = which == 0 ? s0 : which == 1 ? s1 : s2;
    int local = i - (which << lg2);
    float4 x = *(const float4*)&s[(size_t)local * 4];
    u16x4 o;
    o.x = f2bf(x.x); o.y = f2bf(x.y); o.z = f2bf(x.z); o.w = f2bf(x.w);
    *(u16x4*)&dst[(size_t)i * 4] = o;
  }
}

// fp32 [rows][1024] -> bf16 [rows][3072]: [hi | hi | lo] (B side)
__global__ __launch_bounds__(256) void split3_bf16(const float* __restrict__ src,
                                                   ushort_t* __restrict__ dst, int n) {
  int i = blockIdx.x * blockDim.x + threadIdx.x;
  int stride = gridDim.x * blockDim.x;
  for (; i < n; i += stride) {
    int r = i >> 10, c = i & 1023;
    float x = src[i];
    unsigned short hi = f2bf(x);
    unsigned short lo = f2bf(x - bf2f(hi));
    ushort_t* row = dst + (size_t)r * 3072;
    row[c] = hi; row[1024 + c] = hi; row[2048 + c] = lo;
  }
}

// ---------------- merged QKV projection GEMM ----------------
__global__ __launch_bounds__(256) void gemm_qkv(
    const ushort_t* __restrict__ qbf, const ushort_t* __restrict__ kbf,
    const ushort_t* __restrict__ vbf, const ushort_t* __restrict__ Wqb,
    const ushort_t* __restrict__ Wkb, const ushort_t* __restrict__ Wvb,
    const float* __restrict__ bq, const float* __restrict__ bk,
    const float* __restrict__ bv, ushort_t* __restrict__ qhb,
    ushort_t* __restrict__ khb, ushort_t* __restrict__ vT) {
  __shared__ ushort_t As[2][128 * 32];
  __shared__ ushort_t Bs[2][128 * 32];
  const int t = threadIdx.x;
  const int lane = t & 63;
  const int w = t >> 6;
  const int wr = w >> 1, wc = w & 1;
  const int bid = blockIdx.x;
  const int mt = bid / 24, ntg = bid % 24;
  const int which = ntg >> 3, nt = ntg & 7;
  const ushort_t* A  = which == 0 ? qbf : which == 1 ? kbf : vbf;
  const ushort_t* Bw = which == 0 ? Wqb : which == 1 ? Wkb : Wvb;
  const float* bias  = which == 0 ? bq  : which == 1 ? bk  : bv;
  const int m0 = mt * 128, n0 = nt * 128;
  const int r16 = lane & 15, kb = lane >> 4;

  f32x4 acc[4][4];
#pragma unroll
  for (int mi = 0; mi < 4; ++mi)
#pragma unroll
    for (int ni = 0; ni < 4; ++ni) acc[mi][ni] = (f32x4){0.f, 0.f, 0.f, 0.f};

  auto STAGE = [&](int buf, int k0) {
#pragma unroll
    for (int i = 0; i < 2; ++i) {
      int c = i * 256 + t;
      int row = c >> 2, kc = (c & 3) * 8;
      gl_lds16(&A[(size_t)(m0 + row) * 1024 + k0 + kc], &As[buf][c * 8]);
      gl_lds16(&Bw[(size_t)(n0 + row) * 1024 + k0 + kc], &Bs[buf][c * 8]);
    }
  };

  STAGE(0, 0);
  __syncthreads();
  int cur = 0;
  for (int kt = 0; kt < 32; ++kt) {
    if (kt + 1 < 32) STAGE(cur ^ 1, (kt + 1) * 32);
    short8 af[4], bf[4];
#pragma unroll
    for (int mi = 0; mi < 4; ++mi)
      af[mi] = *(const short8*)&As[cur][(wr * 64 + mi * 16 + r16) * 32 + kb * 8];
#pragma unroll
    for (int ni = 0; ni < 4; ++ni)
      bf[ni] = *(const short8*)&Bs[cur][(wc * 64 + ni * 16 + r16) * 32 + kb * 8];
#pragma unroll
    for (int mi = 0; mi < 4; ++mi)
#pragma unroll
      for (int ni = 0; ni < 4; ++ni)
        acc[mi][ni] = __builtin_amdgcn_mfma_f32_16x16x32_bf16(af[mi], bf[ni], acc[mi][ni], 0, 0, 0);
    __syncthreads();
    cur ^= 1;
  }

  const int rowD = (lane >> 4) * 4;
#pragma unroll
  for (int mi = 0; mi < 4; ++mi) {
#pragma unroll
    for (int ni = 0; ni < 4; ++ni) {
      int n = n0 + wc * 64 + ni * 16 + (lane & 15);
      float bv4 = bias[n];
      int mbase = m0 + wr * 64 + mi * 16 + rowD;
      float vals[4];
#pragma unroll
      for (int j = 0; j < 4; ++j) vals[j] = acc[mi][ni][j] + bv4;
      int hh = n >> 6, d = n & 63;
      if (which == 0) {
#pragma unroll
        for (int j = 0; j < 4; ++j) {
          int m = mbase + j;
          int b = m >> 9, l = m & 511;
          qhb[(((size_t)(b * 16 + hh)) * 512 + l) * 64 + d] = f2bf(vals[j]);
        }
      } else if (which == 1) {
#pragma unroll
        for (int j = 0; j < 4; ++j) {
          int m = mbase + j;
          int b = m >> 9, r = m & 511;
          khb[(((size_t)(b * 16 + hh)) * 512 + r) * 64 + d] = f2bf(vals[j]);
        }
      } else {
        int b = mbase >> 9, r = mbase & 511;
        u16x4 pkv;
        pkv.x = f2bf(vals[0]); pkv.y = f2bf(vals[1]);
        pkv.z = f2bf(vals[2]); pkv.w = f2bf(vals[3]);
        *(u16x4*)&vT[(((size_t)(b * 16 + hh)) * 64 + d) * 512 + r] = pkv;
      }
    }
  }
}

// ---------------- final O-projection GEMM (K=3072 split) ----------------
__global__ __launch_bounds__(256) void gemm_out(const ushort_t* __restrict__ A,
                                                const ushort_t* __restrict__ Bw,
                                                const float* __restrict__ bias,
                                                float* __restrict__ Cout) {
  __shared__ ushort_t As[2][128 * 32];
  __shared__ ushort_t Bs[2][128 * 32];
  const int t = threadIdx.x;
  const int lane = t & 63;
  const int w = t >> 6;
  const int wr = w >> 1, wc = w & 1;
  const int mt = blockIdx.x >> 3, nt = blockIdx.x & 7;
  const int m0 = mt * 128, n0 = nt * 128;
  const int r16 = lane & 15, kb = lane >> 4;

  f32x4 acc[4][4];
#pragma unroll
  for (int mi = 0; mi < 4; ++mi)
#pragma unroll
    for (int ni = 0; ni < 4; ++ni) acc[mi][ni] = (f32x4){0.f, 0.f, 0.f, 0.f};

  auto STAGE = [&](int buf, int k0) {
#pragma unroll
    for (int i = 0; i < 2; ++i) {
      int c = i * 256 + t;
      int row = c >> 2, kc = (c & 3) * 8;
      gl_lds16(&A[(size_t)(m0 + row) * 3072 + k0 + kc], &As[buf][c * 8]);
      gl_lds16(&Bw[(size_t)(n0 + row) * 3072 + k0 + kc], &Bs[buf][c * 8]);
    }
  };

  STAGE(0, 0);
  __syncthreads();
  int cur = 0;
  for (int kt = 0; kt < 96; ++kt) {
    if (kt + 1 < 96) STAGE(cur ^ 1, (kt + 1) * 32);
    short8 af[4], bf[4];
#pragma unroll
    for (int mi = 0; mi < 4; ++mi)
      af[mi] = *(const short8*)&As[cur][(wr * 64 + mi * 16 + r16) * 32 + kb * 8];
#pragma unroll
    for (int ni = 0; ni < 4; ++ni)
      bf[ni] = *(const short8*)&Bs[cur][(wc * 64 + ni * 16 + r16) * 32 + kb * 8];
#pragma unroll
    for (int mi = 0; mi < 4; ++mi)
#pragma unroll
      for (int ni = 0; ni < 4; ++ni)
        acc[mi][ni] = __builtin_amdgcn_mfma_f32_16x16x32_bf16(af[mi], bf[ni], acc[mi][ni], 0, 0, 0);
    __syncthreads();
    cur ^= 1;
  }

  const int rowD = (lane >> 4) * 4;
#pragma unroll
  for (int mi = 0; mi < 4; ++mi) {
#pragma unroll
    for (int ni = 0; ni < 4; ++ni) {
      int n = n0 + wc * 64 + ni * 16 + (lane & 15);
      float bv = bias[n];
      int mbase = m0 + wr * 64 + mi * 16 + rowD;
#pragma unroll
      for (int j = 0; j < 4; ++j)
        Cout[(size_t)(mbase + j) * 1024 + n] = acc[mi][ni][j] + bv;
    }
  }
}

// ---------------- fused attention: DMA rel, r-tile=8, 2 wg/CU ----------------
// grid: 512 wgs (16 h x 32 l-tiles of 16, XCD-pinned). 256 thr = 4 waves.
// LDS 78.6 KB -> 2 wg/CU. Wave w: batches {2w,2w+1}; DMAs rel l-rows 4w..4w+3.
// 64 iterations of 8 r-rows. Score rows lg>=2 masked (dup K rows), PV k>=8 zero.
// All q fragments hoisted to registers (iteration-invariant).
__global__ __launch_bounds__(256, 2) void attn_mfma(
    const ushort_t* __restrict__ qhb, const ushort_t* __restrict__ khb,
    const ushort_t* __restrict__ vT, const float* __restrict__ rel,
    const int* __restrict__ mask, ushort_t* __restrict__ Abig) {
  __shared__ float relL[2][16][8][64];   // 64 KB, dbuf rel tiles
  __shared__ float sp2[2][8][17][12];    // 12.75 KB, rel-score exchange
  const int t = threadIdx.x;
  const int w = t >> 6, lane = t & 63, lh = lane & 15, lg = lane >> 4;
  const int w4 = w * 4;
  const int bid = blockIdx.x;
  const int slot = bid & 7, grp = bid >> 3;
  const int h = slot * 2 + (grp & 1);         // heads {2s,2s+1} pinned to XCD s
  const int l0 = (grp >> 1) * 16;
  const int b0 = w * 2;
  const int off = (grp * 21) & 63;            // staggered start (64 r-steps)

  // ---- hoisted q fragments (iteration-invariant), direct global loads ----
  short8 qb0[2], qb1[2];   // phase-2 B operand: n = l (lane lh), k = d
#pragma unroll
  for (int bh = 0; bh < 2; ++bh) {
    const ushort_t* qp = &qhb[(((size_t)((b0 + bh) * 16 + h)) * 512 + l0 + lh) * 64 + lg * 8];
    qb0[bh] = *(const short8*)qp;
    qb1[bh] = *(const short8*)(qp + 32);
  }
  short8 q0f[4], q1f[4];   // phase-1 B operand: n = batch (lane lh&7), k = d
#pragma unroll
  for (int li = 0; li < 4; ++li) {
    const ushort_t* qp = &qhb[(((size_t)((lh & 7) * 16 + h)) * 512 + l0 + w4 + li) * 64 + lg * 8];
    q0f[li] = *(const short8*)qp;
    q1f[li] = *(const short8*)(qp + 32);
  }

  // DMA one rel half-tile: this wave's 4 l-rows x 8 r x 256B = 8 instrs of 1KB
  const int rdel = lane >> 4;       // r advance within 4-row chunk
  const int blk = lane & 15;        // 16B block position within 256B row
  auto DMA_REL = [&](int buf, int r0_) {
#pragma unroll
    for (int j = 0; j < 8; ++j) {
      const int li = j >> 1;
      const int rr4 = (j & 1) * 4;
      const int rl = rr4 + rdel;              // 0..7
      const int blkp = blk ^ rl;              // source block for swizzled position
      const float* src = rel +
          ((size_t)(l0 + w4 + li) * 512 + r0_ + rl) * 1024 + h * 64 + blkp * 4;
      gl_lds16(src, &relL[buf][w4 + li][rr4][0]);
    }
  };

  f32x4 O[2][4];
#pragma unroll
  for (int i = 0; i < 2; ++i)
#pragma unroll
    for (int j = 0; j < 4; ++j) O[i][j] = (f32x4){0.f, 0.f, 0.f, 0.f};
  float m_run[2] = {-1e30f, -1e30f}, s_run[2] = {0.f, 0.f};

  DMA_REL(0, (off & 63) * 8);       // tile 0 in flight

#pragma unroll 1
  for (int it = 0; it < 64; ++it) {
    const int r0 = ((it + off) & 63) * 8;
    const int cur = it & 1;

    // ---- issue next tile's 8 DMAs; wait so only they remain outstanding ----
    __builtin_amdgcn_sched_barrier(0);
    DMA_REL(cur ^ 1, (((it + 1 + off) & 63)) * 8);   // it=63 wraps: harmless dummy
    __builtin_amdgcn_sched_barrier(0);
    asm volatile("s_waitcnt vmcnt(8)" ::: "memory"); // tile it ready; next 8 in flight
    __builtin_amdgcn_sched_barrier(0);

    // K / V / mask loads (consumed in phase 2; land under phase 1)
    short8 kf[2][2], vf[2][4];
#pragma unroll
    for (int bh = 0; bh < 2; ++bh) {
#pragma unroll
      for (int kb = 0; kb < 2; ++kb)
        kf[bh][kb] = *(const short8*)&khb[(((size_t)((b0 + bh) * 16 + h)) * 512 + r0 + (lh & 7)) * 64 + kb * 32 + lg * 8];
#pragma unroll
      for (int dt = 0; dt < 4; ++dt)
        vf[bh][dt] = *(const short8*)&vT[(((size_t)((b0 + bh) * 16 + h)) * 64 + dt * 16 + lh) * 512 + r0 + lg * 8];
    }
    int4 mk = *(const int4*)&mask[(size_t)(l0 + lh) * 512 + r0 + (lg & 1) * 4];

    // ---- phase 1: rel-term MFMA from LDS (own-wave rows; no barrier needed) ----
#pragma unroll
    for (int li = 0; li < 4; ++li) {
      const int l = w4 + li;
      const float* row = &relL[cur][l][lh & 7][0];
      const int s = lh & 7;
      frag_u a0, a1;
      {
        int bb = lg * 2;
        f32x4 Ra = *(const f32x4*)(row + ((bb ^ s) * 4));
        f32x4 Rb = *(const f32x4*)(row + (((bb + 1) ^ s) * 4));
        a0.w[0] = pk_bf16(Ra[0], Ra[1]); a0.w[1] = pk_bf16(Ra[2], Ra[3]);
        a0.w[2] = pk_bf16(Rb[0], Rb[1]); a0.w[3] = pk_bf16(Rb[2], Rb[3]);
      }
      {
        int bb = 8 + lg * 2;
        f32x4 Ra = *(const f32x4*)(row + ((bb ^ s) * 4));
        f32x4 Rb = *(const f32x4*)(row + (((bb + 1) ^ s) * 4));
        a1.w[0] = pk_bf16(Ra[0], Ra[1]); a1.w[1] = pk_bf16(Ra[2], Ra[3]);
        a1.w[2] = pk_bf16(Rb[0], Rb[1]); a1.w[3] = pk_bf16(Rb[2], Rb[3]);
      }
      f32x4 acc = (f32x4){0.f, 0.f, 0.f, 0.f};
      acc = __builtin_amdgcn_mfma_f32_16x16x32_bf16(a0.s, q0f[li], acc, 0, 0, 0);
      acc = __builtin_amdgcn_mfma_f32_16x16x32_bf16(a1.s, q1f[li], acc, 0, 0, 0);
      if (lh < 8 && lg < 2) *(f32x4*)&sp2[cur][lh][l][lg * 4] = acc;
    }

    barrier_lds();   // sp2 visible to all waves (lgkm only; DMAs stay in flight)

    // ---- phase 2: QK + softmax + PV (8 valid r rows; lg>=2 masked) ----
    __builtin_amdgcn_s_setprio(1);
    const bool vrow = (lg < 2);
#pragma unroll
    for (int bh = 0; bh < 2; ++bh) {
      f32x4 s1 = (f32x4){0.f, 0.f, 0.f, 0.f};
      s1 = __builtin_amdgcn_mfma_f32_16x16x32_bf16(kf[bh][0], qb0[bh], s1, 0, 0, 0);
      s1 = __builtin_amdgcn_mfma_f32_16x16x32_bf16(kf[bh][1], qb1[bh], s1, 0, 0, 0);
      f32x4 s2 = *(const f32x4*)&sp2[cur][b0 + bh][lh][lg * 4];
      f32x4 S;
      S[0] = (vrow && mk.x != 0) ? (s1[0] * 0.125f + s2[0]) : -1e9f;
      S[1] = (vrow && mk.y != 0) ? (s1[1] * 0.125f + s2[1]) : -1e9f;
      S[2] = (vrow && mk.z != 0) ? (s1[2] * 0.125f + s2[2]) : -1e9f;
      S[3] = (vrow && mk.w != 0) ? (s1[3] * 0.125f + s2[3]) : -1e9f;
      float mt = fmaxf(fmaxf(S[0], S[1]), fmaxf(S[2], S[3]));
      mt = fmaxf(mt, __shfl_xor(mt, 16));
      mt = fmaxf(mt, __shfl_xor(mt, 32));
      float mn = fmaxf(m_run[bh], mt);
      float fsc = __expf(m_run[bh] - mn);
      f32x4 P;
      P[0] = __expf(S[0] - mn); P[1] = __expf(S[1] - mn);
      P[2] = __expf(S[2] - mn); P[3] = __expf(S[3] - mn);
      float ps = P[0] + P[1] + P[2] + P[3];
      ps += __shfl_xor(ps, 16);
      ps += __shfl_xor(ps, 32);
      s_run[bh] = s_run[bh] * fsc + ps;
      m_run[bh] = mn;
#pragma unroll
      for (int dt = 0; dt < 4; ++dt) O[bh][dt] *= fsc;
      // P (C-layout) -> B-fragment (k=r): rows>=8 are exactly 0, k>=16 zeroed
      u32 pk0 = pk_bf16(P[0], P[1]), pk1 = pk_bf16(P[2], P[3]);
      int s0l = (lh + 32 * lg) & 63;
      u32 w0 = (u32)__shfl((int)pk0, s0l), w1 = (u32)__shfl((int)pk1, s0l);
      u32 w2 = (u32)__shfl((int)pk0, s0l + 16), w3 = (u32)__shfl((int)pk1, s0l + 16);
      bool vld = (lg < 2);
      frag_u pb;
      pb.w[0] = vld ? w0 : 0u; pb.w[1] = vld ? w1 : 0u;
      pb.w[2] = vld ? w2 : 0u; pb.w[3] = vld ? w3 : 0u;
#pragma unroll
      for (int dt = 0; dt < 4; ++dt)
        O[bh][dt] = __builtin_amdgcn_mfma_f32_16x16x32_bf16(vf[bh][dt], pb.s, O[bh][dt], 0, 0, 0);
    }
    __builtin_amdgcn_s_setprio(0);
  }

  // ---- epilogue: O /= s; hi/lo/hi bf16 split into Abig [b*512+l][3072] ----
#pragma unroll
  for (int bh = 0; bh < 2; ++bh) {
    float inv = 1.0f / s_run[bh];
    ushort_t* rowp = &Abig[(size_t)((b0 + bh) * 512 + l0 + lh) * 3072];
#pragma unroll
    for (int dt = 0; dt < 4; ++dt) {
      int c = h * 64 + dt * 16 + lg * 4;
      f32x4 o = O[bh][dt];
      float x0 = o[0] * inv, x1 = o[1] * inv, x2 = o[2] * inv, x3 = o[3] * inv;
      u16x4 hi, lo;
      hi.x = f2bf(x0); lo.x = f2bf(x0 - bf2f(hi.x));
      hi.y = f2bf(x1); lo.y = f2bf(x1 - bf2f(hi.y));
      hi.z = f2bf(x2); lo.z = f2bf(x2 - bf2f(hi.z));
      hi.w = f2bf(x3); lo.w = f2bf(x3 - bf2f(hi.w));
      *(u16x4*)&rowp[c] = hi;
      *(u16x4*)&rowp[1024 + c] = lo;
      *(u16x4*)&rowp[2048 + c] = hi;
    }
  }
}

// ---------------- launcher ----------------
extern "C" void kernel_launch(void* const* d_in, const int* in_sizes, int n_in,
                              void* d_out, int out_size, void* d_ws, size_t ws_size,
                              hipStream_t stream) {
  const float* q    = (const float*)d_in[0];
  const float* k    = (const float*)d_in[1];
  const float* v    = (const float*)d_in[2];
  const float* rel  = (const float*)d_in[3];
  const int*   mask = (const int*)d_in[4];
  const float* Wq   = (const float*)d_in[5];
  const float* bq   = (const float*)d_in[6];
  const float* Wk   = (const float*)d_in[7];
  const float* bk   = (const float*)d_in[8];
  const float* Wv   = (const float*)d_in[9];
  const float* bv   = (const float*)d_in[10];
  const float* Wo   = (const float*)d_in[11];
  const float* bo   = (const float*)d_in[12];
  float* out = (float*)d_out;

  char* ws = (char*)d_ws;
  ushort_t* qhb = (ushort_t*)(ws);                       // 8.39 MB bf16 [b][h][l][d]
  ushort_t* khb = (ushort_t*)(ws + 16777216);            // 8.39 MB bf16 [b][h][r][d]
  ushort_t* vT  = (ushort_t*)(ws + 16777216 + 8388608);  // 8.39 MB bf16 [b][h][d][r]
  ushort_t* X   = (ushort_t*)(ws + 33554432);            // 25.17 MB: qbf/kbf/vbf then Abig
  ushort_t* Y   = (ushort_t*)(ws + 58720256);            // 6.29 MB: W*bf then Wo split
  ushort_t* qbf = X;
  ushort_t* kbf = X + 4194304;
  ushort_t* vbf = X + 8388608;
  ushort_t* Wqb = Y;
  ushort_t* Wkb = Y + 1048576;
  ushort_t* Wvb = Y + 2097152;

  to_bf16_3<<<1536, 256, 0, stream>>>(q, k, v, X, 20, 3145728);
  to_bf16_3<<<384, 256, 0, stream>>>(Wq, Wk, Wv, Y, 18, 786432);

  gemm_qkv<<<768, 256, 0, stream>>>(qbf, kbf, vbf, Wqb, Wkb, Wvb,
                                    bq, bk, bv, qhb, khb, vT);

  split3_bf16<<<1024, 256, 0, stream>>>(Wo, Y, 1048576);

  attn_mfma<<<512, 256, 0, stream>>>(qhb, khb, vT, rel, mask, X);

  gemm_out<<<256, 256, 0, stream>>>(X, Y, bo, out);
}

// Round 11
// 441.389 us; speedup vs baseline: 1.2266x; 1.2266x over previous
//
#include <hip/hip_runtime.h>

// ---------------- types ----------------
typedef __attribute__((ext_vector_type(8))) short short8;
typedef __attribute__((ext_vector_type(4))) float f32x4;
typedef __attribute__((ext_vector_type(4))) unsigned short u16x4;
typedef unsigned int u32;
typedef unsigned short ushort_t;

union frag_u { u32 w[4]; short8 s; };

static __device__ __forceinline__ unsigned short f2bf(float x) {
  union { float f; unsigned u; } v; v.f = x;
  unsigned r = v.u + 0x7fffu + ((v.u >> 16) & 1u);   // round-to-nearest-even
  return (unsigned short)(r >> 16);
}
static __device__ __forceinline__ float bf2f(unsigned short h) {
  union { unsigned u; float f; } v; v.u = ((unsigned)h) << 16;
  return v.f;
}
static __device__ __forceinline__ u32 pk_bf16(float a, float b) {
  u32 r;
  asm("v_cvt_pk_bf16_f32 %0, %1, %2" : "=v"(r) : "v"(a), "v"(b));
  return r;
}

// async global->LDS, 16B per lane (linear LDS dest = wave base + lane*16)
static __device__ __forceinline__ void gl_lds16(const void* g, void* s) {
  __builtin_amdgcn_global_load_lds(
      (const __attribute__((address_space(1))) void*)g,
      (__attribute__((address_space(3))) void*)s, 16, 0, 0);
}

// ---------------- fp32 -> bf16, three contiguous regions ----------------
__global__ __launch_bounds__(256) void to_bf16_3(const float* __restrict__ s0,
                                                 const float* __restrict__ s1,
                                                 const float* __restrict__ s2,
                                                 ushort_t* __restrict__ dst,
                                                 int lg2, int n4) {
  int i = blockIdx.x * blockDim.x + threadIdx.x;
  int stride = gridDim.x * blockDim.x;
  for (; i < n4; i += stride) {
    int which = i >> lg2;
    const float* s = which == 0 ? s0 : which == 1 ? s1 : s2;
    int local = i - (which << lg2);
    float4 x = *(const float4*)&s[(size_t)local * 4];
    u16x4 o;
    o.x = f2bf(x.x); o.y = f2bf(x.y); o.z = f2bf(x.z); o.w = f2bf(x.w);
    *(u16x4*)&dst[(size_t)i * 4] = o;
  }
}

// fp32 [rows][1024] -> bf16 [rows][3072]: [hi | hi | lo] (B side)
__global__ __launch_bounds__(256) void split3_bf16(const float* __restrict__ src,
                                                   ushort_t* __restrict__ dst, int n) {
  int i = blockIdx.x * blockDim.x + threadIdx.x;
  int stride = gridDim.x * blockDim.x;
  for (; i < n; i += stride) {
    int r = i >> 10, c = i & 1023;
    float x = src[i];
    unsigned short hi = f2bf(x);
    unsigned short lo = f2bf(x - bf2f(hi));
    ushort_t* row = dst + (size_t)r * 3072;
    row[c] = hi; row[1024 + c] = hi; row[2048 + c] = lo;
  }
}

// ---------------- merged QKV projection GEMM ----------------
// 768 wgs: mt = bid/24, ntg = bid%24: which = ntg>>3, nt = ntg&7
// which 0: qhb bf16 [b][h][l][d]; 1: khb bf16 [b][h][r][d]; 2: vT bf16 [b][h][d][r]
__global__ __launch_bounds__(256) void gemm_qkv(
    const ushort_t* __restrict__ qbf, const ushort_t* __restrict__ kbf,
    const ushort_t* __restrict__ vbf, const ushort_t* __restrict__ Wqb,
    const ushort_t* __restrict__ Wkb, const ushort_t* __restrict__ Wvb,
    const float* __restrict__ bq, const float* __restrict__ bk,
    const float* __restrict__ bv, ushort_t* __restrict__ qhb,
    ushort_t* __restrict__ khb, ushort_t* __restrict__ vT) {
  __shared__ ushort_t As[2][128 * 32];
  __shared__ ushort_t Bs[2][128 * 32];
  const int t = threadIdx.x;
  const int lane = t & 63;
  const int w = t >> 6;
  const int wr = w >> 1, wc = w & 1;
  const int bid = blockIdx.x;
  const int mt = bid / 24, ntg = bid % 24;
  const int which = ntg >> 3, nt = ntg & 7;
  const ushort_t* A  = which == 0 ? qbf : which == 1 ? kbf : vbf;
  const ushort_t* Bw = which == 0 ? Wqb : which == 1 ? Wkb : Wvb;
  const float* bias  = which == 0 ? bq  : which == 1 ? bk  : bv;
  const int m0 = mt * 128, n0 = nt * 128;
  const int r16 = lane & 15, kb = lane >> 4;

  f32x4 acc[4][4];
#pragma unroll
  for (int mi = 0; mi < 4; ++mi)
#pragma unroll
    for (int ni = 0; ni < 4; ++ni) acc[mi][ni] = (f32x4){0.f, 0.f, 0.f, 0.f};

  auto STAGE = [&](int buf, int k0) {
#pragma unroll
    for (int i = 0; i < 2; ++i) {
      int c = i * 256 + t;
      int row = c >> 2, kc = (c & 3) * 8;
      gl_lds16(&A[(size_t)(m0 + row) * 1024 + k0 + kc], &As[buf][c * 8]);
      gl_lds16(&Bw[(size_t)(n0 + row) * 1024 + k0 + kc], &Bs[buf][c * 8]);
    }
  };

  STAGE(0, 0);
  __syncthreads();
  int cur = 0;
  for (int kt = 0; kt < 32; ++kt) {
    if (kt + 1 < 32) STAGE(cur ^ 1, (kt + 1) * 32);
    short8 af[4], bf[4];
#pragma unroll
    for (int mi = 0; mi < 4; ++mi)
      af[mi] = *(const short8*)&As[cur][(wr * 64 + mi * 16 + r16) * 32 + kb * 8];
#pragma unroll
    for (int ni = 0; ni < 4; ++ni)
      bf[ni] = *(const short8*)&Bs[cur][(wc * 64 + ni * 16 + r16) * 32 + kb * 8];
#pragma unroll
    for (int mi = 0; mi < 4; ++mi)
#pragma unroll
      for (int ni = 0; ni < 4; ++ni)
        acc[mi][ni] = __builtin_amdgcn_mfma_f32_16x16x32_bf16(af[mi], bf[ni], acc[mi][ni], 0, 0, 0);
    __syncthreads();
    cur ^= 1;
  }

  const int rowD = (lane >> 4) * 4;
#pragma unroll
  for (int mi = 0; mi < 4; ++mi) {
#pragma unroll
    for (int ni = 0; ni < 4; ++ni) {
      int n = n0 + wc * 64 + ni * 16 + (lane & 15);
      float bv4 = bias[n];
      int mbase = m0 + wr * 64 + mi * 16 + rowD;
      float vals[4];
#pragma unroll
      for (int j = 0; j < 4; ++j) vals[j] = acc[mi][ni][j] + bv4;
      int hh = n >> 6, d = n & 63;
      if (which == 0) {
#pragma unroll
        for (int j = 0; j < 4; ++j) {
          int m = mbase + j;
          int b = m >> 9, l = m & 511;
          qhb[(((size_t)(b * 16 + hh)) * 512 + l) * 64 + d] = f2bf(vals[j]);
        }
      } else if (which == 1) {
#pragma unroll
        for (int j = 0; j < 4; ++j) {
          int m = mbase + j;
          int b = m >> 9, r = m & 511;
          khb[(((size_t)(b * 16 + hh)) * 512 + r) * 64 + d] = f2bf(vals[j]);
        }
      } else {
        int b = mbase >> 9, r = mbase & 511;
        u16x4 pkv;
        pkv.x = f2bf(vals[0]); pkv.y = f2bf(vals[1]);
        pkv.z = f2bf(vals[2]); pkv.w = f2bf(vals[3]);
        *(u16x4*)&vT[(((size_t)(b * 16 + hh)) * 64 + d) * 512 + r] = pkv;
      }
    }
  }
}

// ---------------- final O-projection GEMM (K=3072 split) ----------------
__global__ __launch_bounds__(256) void gemm_out(const ushort_t* __restrict__ A,
                                                const ushort_t* __restrict__ Bw,
                                                const float* __restrict__ bias,
                                                float* __restrict__ Cout) {
  __shared__ ushort_t As[2][128 * 32];
  __shared__ ushort_t Bs[2][128 * 32];
  const int t = threadIdx.x;
  const int lane = t & 63;
  const int w = t >> 6;
  const int wr = w >> 1, wc = w & 1;
  const int mt = blockIdx.x >> 3, nt = blockIdx.x & 7;
  const int m0 = mt * 128, n0 = nt * 128;
  const int r16 = lane & 15, kb = lane >> 4;

  f32x4 acc[4][4];
#pragma unroll
  for (int mi = 0; mi < 4; ++mi)
#pragma unroll
    for (int ni = 0; ni < 4; ++ni) acc[mi][ni] = (f32x4){0.f, 0.f, 0.f, 0.f};

  auto STAGE = [&](int buf, int k0) {
#pragma unroll
    for (int i = 0; i < 2; ++i) {
      int c = i * 256 + t;
      int row = c >> 2, kc = (c & 3) * 8;
      gl_lds16(&A[(size_t)(m0 + row) * 3072 + k0 + kc], &As[buf][c * 8]);
      gl_lds16(&Bw[(size_t)(n0 + row) * 3072 + k0 + kc], &Bs[buf][c * 8]);
    }
  };

  STAGE(0, 0);
  __syncthreads();
  int cur = 0;
  for (int kt = 0; kt < 96; ++kt) {
    if (kt + 1 < 96) STAGE(cur ^ 1, (kt + 1) * 32);
    short8 af[4], bf[4];
#pragma unroll
    for (int mi = 0; mi < 4; ++mi)
      af[mi] = *(const short8*)&As[cur][(wr * 64 + mi * 16 + r16) * 32 + kb * 8];
#pragma unroll
    for (int ni = 0; ni < 4; ++ni)
      bf[ni] = *(const short8*)&Bs[cur][(wc * 64 + ni * 16 + r16) * 32 + kb * 8];
#pragma unroll
    for (int mi = 0; mi < 4; ++mi)
#pragma unroll
      for (int ni = 0; ni < 4; ++ni)
        acc[mi][ni] = __builtin_amdgcn_mfma_f32_16x16x32_bf16(af[mi], bf[ni], acc[mi][ni], 0, 0, 0);
    __syncthreads();
    cur ^= 1;
  }

  const int rowD = (lane >> 4) * 4;
#pragma unroll
  for (int mi = 0; mi < 4; ++mi) {
#pragma unroll
    for (int ni = 0; ni < 4; ++ni) {
      int n = n0 + wc * 64 + ni * 16 + (lane & 15);
      float bv = bias[n];
      int mbase = m0 + wr * 64 + mi * 16 + rowD;
#pragma unroll
      for (int j = 0; j < 4; ++j)
        Cout[(size_t)(mbase + j) * 1024 + n] = acc[mi][ni][j] + bv;
    }
  }
}

// ---------------- fused attention, full MFMA (round-6 structure, no stagger) ----
// grid: 512 wgs. slot=bid&7 -> XCD; grp=bid>>3: h = slot*2 + (grp&1), l0=(grp>>1)*16.
// CU-co-resident pair = heads {2s,2s+1} with the same l0, now marching identical
// r-tiles in lockstep (stagger removed) so DRAM pages of each rel row are covered
// concurrently by all sharers.
__global__ __launch_bounds__(256, 2) void attn_mfma(
    const ushort_t* __restrict__ qhb, const ushort_t* __restrict__ khb,
    const ushort_t* __restrict__ vT, const float* __restrict__ rel,
    const int* __restrict__ mask, ushort_t* __restrict__ Abig) {
  __shared__ ushort_t qs[8][16][64];          // bf16 q [b][l][8 blocks of 8, swizzled]
  __shared__ float sp2[2][8][17][20];         // rel scores [buf][b][l(+1 pad)][r(+pad)]
  const int t = threadIdx.x;
  const int w = t >> 6, lane = t & 63, lh = lane & 15, lg = lane >> 4;
  const int bid = blockIdx.x;
  const int slot = bid & 7, grp = bid >> 3;
  const int h = slot * 2 + (grp & 1);         // heads {2s,2s+1} pinned to XCD s
  const int l0 = (grp >> 1) * 16;
  const int b0 = w * 2;

  // ---- stage q (bf16) into swizzled qs ----
  {
    int idx = t * 32;
    int b = idx >> 10, l = (idx >> 6) & 15, d0 = idx & 63;   // d0 in {0,32}
    const ushort_t* src = &qhb[(((size_t)(b * 16 + h)) * 512 + l0 + l) * 64 + d0];
    int xr = (l & 7) ^ b;
#pragma unroll
    for (int jj = 0; jj < 4; ++jj) {
      short8 vq = *(const short8*)&src[jj * 8];
      int pos = ((d0 >> 3) + jj) ^ xr;
      *(short8*)&qs[b][l][pos * 8] = vq;
    }
  }

  f32x4 R[16];
  const float* relbase = &rel[(size_t)(l0 + w * 4) * 512 * 1024 + h * 64 + lg * 8];
  auto LOAD_REL = [&](int r0_) {
#pragma unroll
    for (int li = 0; li < 4; ++li) {
      const float* rp = relbase + ((size_t)li * 512 + r0_ + lh) * 1024;
#pragma unroll
      for (int kb = 0; kb < 2; ++kb) {
        R[li * 4 + kb * 2 + 0] = *(const f32x4*)&rp[kb * 32];
        R[li * 4 + kb * 2 + 1] = *(const f32x4*)&rp[kb * 32 + 4];
      }
    }
  };
  LOAD_REL(0);

  f32x4 O[2][4];                              // [b-hat][d-tile], rows d=4lg+j, col l=lh
#pragma unroll
  for (int i = 0; i < 2; ++i)
#pragma unroll
    for (int j = 0; j < 4; ++j) O[i][j] = (f32x4){0.f, 0.f, 0.f, 0.f};
  float m_run[2] = {-1e30f, -1e30f}, s_run[2] = {0.f, 0.f};

  __syncthreads();

#pragma unroll 1
  for (int it = 0; it < 32; ++it) {
    const int r0 = it * 16;
    const int cur = it & 1;

    // K / V / mask loads for this tile (consumed in phase 2)
    short8 kf[2][2], vf[2][4];
#pragma unroll
    for (int bh = 0; bh < 2; ++bh) {
#pragma unroll
      for (int kb = 0; kb < 2; ++kb)
        kf[bh][kb] = *(const short8*)&khb[(((size_t)((b0 + bh) * 16 + h)) * 512 + r0 + lh) * 64 + kb * 32 + lg * 8];
#pragma unroll
      for (int dt = 0; dt < 4; ++dt)
        vf[bh][dt] = *(const short8*)&vT[(((size_t)((b0 + bh) * 16 + h)) * 64 + dt * 16 + lh) * 512 + r0 + lg * 8];
    }
    int4 mk = *(const int4*)&mask[(size_t)(l0 + lh) * 512 + r0 + lg * 4];

    // ---- phase 1: rel-term MFMA (consumes R) -> sp2[cur] ----
#pragma unroll
    for (int li = 0; li < 4; ++li) {
      frag_u a0, a1;
      f32x4 v00 = R[li * 4 + 0], v01 = R[li * 4 + 1];
      f32x4 v10 = R[li * 4 + 2], v11 = R[li * 4 + 3];
      a0.w[0] = pk_bf16(v00[0], v00[1]); a0.w[1] = pk_bf16(v00[2], v00[3]);
      a0.w[2] = pk_bf16(v01[0], v01[1]); a0.w[3] = pk_bf16(v01[2], v01[3]);
      a1.w[0] = pk_bf16(v10[0], v10[1]); a1.w[1] = pk_bf16(v10[2], v10[3]);
      a1.w[2] = pk_bf16(v11[0], v11[1]); a1.w[3] = pk_bf16(v11[2], v11[3]);
      int l = w * 4 + li;
      int xr2 = (l & 7) ^ (lh & 7);
      short8 q0 = *(const short8*)&qs[lh & 7][l][(lg ^ xr2) * 8];
      short8 q1 = *(const short8*)&qs[lh & 7][l][((4 + lg) ^ xr2) * 8];
      f32x4 acc = (f32x4){0.f, 0.f, 0.f, 0.f};
      acc = __builtin_amdgcn_mfma_f32_16x16x32_bf16(a0.s, q0, acc, 0, 0, 0);
      acc = __builtin_amdgcn_mfma_f32_16x16x32_bf16(a1.s, q1, acc, 0, 0, 0);
      if (lh < 8) *(f32x4*)&sp2[cur][lh][l][lg * 4] = acc;
    }
    // issue next rel tile (R dead after cvt above)
    if (it < 31) LOAD_REL(r0 + 16);

    __syncthreads();

    // ---- phase 2: QK + softmax + PV ----
    __builtin_amdgcn_s_setprio(1);
#pragma unroll
    for (int bh = 0; bh < 2; ++bh) {
      int xqk = (lh & 7) ^ (b0 + bh);
      short8 qb0 = *(const short8*)&qs[b0 + bh][lh][(lg ^ xqk) * 8];
      short8 qb1 = *(const short8*)&qs[b0 + bh][lh][((4 + lg) ^ xqk) * 8];
      f32x4 s1 = (f32x4){0.f, 0.f, 0.f, 0.f};
      s1 = __builtin_amdgcn_mfma_f32_16x16x32_bf16(kf[bh][0], qb0, s1, 0, 0, 0);
      s1 = __builtin_amdgcn_mfma_f32_16x16x32_bf16(kf[bh][1], qb1, s1, 0, 0, 0);
      f32x4 s2 = *(const f32x4*)&sp2[cur][b0 + bh][lh][lg * 4];
      f32x4 S;
      S[0] = (mk.x == 0) ? -1e9f : (s1[0] * 0.125f + s2[0]);
      S[1] = (mk.y == 0) ? -1e9f : (s1[1] * 0.125f + s2[1]);
      S[2] = (mk.z == 0) ? -1e9f : (s1[2] * 0.125f + s2[2]);
      S[3] = (mk.w == 0) ? -1e9f : (s1[3] * 0.125f + s2[3]);
      float mt = fmaxf(fmaxf(S[0], S[1]), fmaxf(S[2], S[3]));
      mt = fmaxf(mt, __shfl_xor(mt, 16));
      mt = fmaxf(mt, __shfl_xor(mt, 32));
      float mn = fmaxf(m_run[bh], mt);
      float fsc = __expf(m_run[bh] - mn);
      f32x4 P;
      P[0] = __expf(S[0] - mn); P[1] = __expf(S[1] - mn);
      P[2] = __expf(S[2] - mn); P[3] = __expf(S[3] - mn);
      float ps = P[0] + P[1] + P[2] + P[3];
      ps += __shfl_xor(ps, 16);
      ps += __shfl_xor(ps, 32);
      s_run[bh] = s_run[bh] * fsc + ps;
      m_run[bh] = mn;
#pragma unroll
      for (int dt = 0; dt < 4; ++dt) O[bh][dt] *= fsc;
      u32 pk0 = pk_bf16(P[0], P[1]), pk1 = pk_bf16(P[2], P[3]);
      int s0l = (lh + 32 * lg) & 63;
      u32 w0 = (u32)__shfl((int)pk0, s0l), w1 = (u32)__shfl((int)pk1, s0l);
      u32 w2 = (u32)__shfl((int)pk0, s0l + 16), w3 = (u32)__shfl((int)pk1, s0l + 16);
      bool vld = (lg < 2);
      frag_u pb;
      pb.w[0] = vld ? w0 : 0u; pb.w[1] = vld ? w1 : 0u;
      pb.w[2] = vld ? w2 : 0u; pb.w[3] = vld ? w3 : 0u;
#pragma unroll
      for (int dt = 0; dt < 4; ++dt)
        O[bh][dt] = __builtin_amdgcn_mfma_f32_16x16x32_bf16(vf[bh][dt], pb.s, O[bh][dt], 0, 0, 0);
    }
    __builtin_amdgcn_s_setprio(0);
  }

  // ---- epilogue: O /= s; hi/lo/hi bf16 split into Abig [b*512+l][3072] ----
#pragma unroll
  for (int bh = 0; bh < 2; ++bh) {
    float inv = 1.0f / s_run[bh];
    ushort_t* rowp = &Abig[(size_t)((b0 + bh) * 512 + l0 + lh) * 3072];
#pragma unroll
    for (int dt = 0; dt < 4; ++dt) {
      int c = h * 64 + dt * 16 + lg * 4;
      f32x4 o = O[bh][dt];
      float x0 = o[0] * inv, x1 = o[1] * inv, x2 = o[2] * inv, x3 = o[3] * inv;
      u16x4 hi, lo;
      hi.x = f2bf(x0); lo.x = f2bf(x0 - bf2f(hi.x));
      hi.y = f2bf(x1); lo.y = f2bf(x1 - bf2f(hi.y));
      hi.z = f2bf(x2); lo.z = f2bf(x2 - bf2f(hi.z));
      hi.w = f2bf(x3); lo.w = f2bf(x3 - bf2f(hi.w));
      *(u16x4*)&rowp[c] = hi;
      *(u16x4*)&rowp[1024 + c] = lo;
      *(u16x4*)&rowp[2048 + c] = hi;
    }
  }
}

// ---------------- launcher ----------------
extern "C" void kernel_launch(void* const* d_in, const int* in_sizes, int n_in,
                              void* d_out, int out_size, void* d_ws, size_t ws_size,
                              hipStream_t stream) {
  const float* q    = (const float*)d_in[0];
  const float* k    = (const float*)d_in[1];
  const float* v    = (const float*)d_in[2];
  const float* rel  = (const float*)d_in[3];
  const int*   mask = (const int*)d_in[4];
  const float* Wq   = (const float*)d_in[5];
  const float* bq   = (const float*)d_in[6];
  const float* Wk   = (const float*)d_in[7];
  const float* bk   = (const float*)d_in[8];
  const float* Wv   = (const float*)d_in[9];
  const float* bv   = (const float*)d_in[10];
  const float* Wo   = (const float*)d_in[11];
  const float* bo   = (const float*)d_in[12];
  float* out = (float*)d_out;

  char* ws = (char*)d_ws;
  ushort_t* qhb = (ushort_t*)(ws);                       // 8.39 MB bf16 [b][h][l][d]
  ushort_t* khb = (ushort_t*)(ws + 16777216);            // 8.39 MB bf16 [b][h][r][d]
  ushort_t* vT  = (ushort_t*)(ws + 16777216 + 8388608);  // 8.39 MB bf16 [b][h][d][r]
  ushort_t* X   = (ushort_t*)(ws + 33554432);            // 25.17 MB: qbf/kbf/vbf then Abig
  ushort_t* Y   = (ushort_t*)(ws + 58720256);            // 6.29 MB: W*bf then Wo split
  ushort_t* qbf = X;
  ushort_t* kbf = X + 4194304;
  ushort_t* vbf = X + 8388608;
  ushort_t* Wqb = Y;
  ushort_t* Wkb = Y + 1048576;
  ushort_t* Wvb = Y + 2097152;

  to_bf16_3<<<1536, 256, 0, stream>>>(q, k, v, X, 20, 3145728);
  to_bf16_3<<<384, 256, 0, stream>>>(Wq, Wk, Wv, Y, 18, 786432);

  gemm_qkv<<<768, 256, 0, stream>>>(qbf, kbf, vbf, Wqb, Wkb, Wvb,
                                    bq, bk, bv, qhb, khb, vT);

  split3_bf16<<<1024, 256, 0, stream>>>(Wo, Y, 1048576);

  attn_mfma<<<512, 256, 0, stream>>>(qhb, khb, vT, rel, mask, X);

  gemm_out<<<256, 256, 0, stream>>>(X, Y, bo, out);
}

// Round 12
// 432.185 us; speedup vs baseline: 1.2527x; 1.0213x over previous
//
#include <hip/hip_runtime.h>

// ---------------- types ----------------
typedef __attribute__((ext_vector_type(8))) short short8;
typedef __attribute__((ext_vector_type(4))) float f32x4;
typedef __attribute__((ext_vector_type(4))) unsigned short u16x4;
typedef unsigned int u32;
typedef unsigned short ushort_t;

union frag_u { u32 w[4]; short8 s; };

static __device__ __forceinline__ unsigned short f2bf(float x) {
  union { float f; unsigned u; } v; v.f = x;
  unsigned r = v.u + 0x7fffu + ((v.u >> 16) & 1u);   // round-to-nearest-even
  return (unsigned short)(r >> 16);
}
static __device__ __forceinline__ float bf2f(unsigned short h) {
  union { unsigned u; float f; } v; v.u = ((unsigned)h) << 16;
  return v.f;
}
static __device__ __forceinline__ u32 pk_bf16(float a, float b) {
  u32 r;
  asm("v_cvt_pk_bf16_f32 %0, %1, %2" : "=v"(r) : "v"(a), "v"(b));
  return r;
}

// async global->LDS, 16B per lane (linear LDS dest = wave base + lane*16)
static __device__ __forceinline__ void gl_lds16(const void* g, void* s) {
  __builtin_amdgcn_global_load_lds(
      (const __attribute__((address_space(1))) void*)g,
      (__attribute__((address_space(3))) void*)s, 16, 0, 0);
}

// ---------------- fp32 -> bf16, three contiguous regions ----------------
__global__ __launch_bounds__(256) void to_bf16_3(const float* __restrict__ s0,
                                                 const float* __restrict__ s1,
                                                 const float* __restrict__ s2,
                                                 ushort_t* __restrict__ dst,
                                                 int lg2, int n4) {
  int i = blockIdx.x * blockDim.x + threadIdx.x;
  int stride = gridDim.x * blockDim.x;
  for (; i < n4; i += stride) {
    int which = i >> lg2;
    const float* s = which == 0 ? s0 : which == 1 ? s1 : s2;
    int local = i - (which << lg2);
    float4 x = *(const float4*)&s[(size_t)local * 4];
    u16x4 o;
    o.x = f2bf(x.x); o.y = f2bf(x.y); o.z = f2bf(x.z); o.w = f2bf(x.w);
    *(u16x4*)&dst[(size_t)i * 4] = o;
  }
}

// fp32 [rows][1024] -> bf16 [rows][3072]: [hi | hi | lo] (B side)
__global__ __launch_bounds__(256) void split3_bf16(const float* __restrict__ src,
                                                   ushort_t* __restrict__ dst, int n) {
  int i = blockIdx.x * blockDim.x + threadIdx.x;
  int stride = gridDim.x * blockDim.x;
  for (; i < n; i += stride) {
    int r = i >> 10, c = i & 1023;
    float x = src[i];
    unsigned short hi = f2bf(x);
    unsigned short lo = f2bf(x - bf2f(hi));
    ushort_t* row = dst + (size_t)r * 3072;
    row[c] = hi; row[1024 + c] = hi; row[2048 + c] = lo;
  }
}

// ---------------- merged QKV projection GEMM (XCD-pinned) ----------------
// 768 wgs: xcd = bid&7; idx = bid>>3 (0..95): which = idx/32, sub = idx&31,
// mt = xcd*4 + (sub>>3), nt = sub&7.  Each XCD's working set: 4 A-row-blocks
// (3 MB) + one weight matrix (2.1 MB) -> L2-resident.
__global__ __launch_bounds__(256) void gemm_qkv(
    const ushort_t* __restrict__ qbf, const ushort_t* __restrict__ kbf,
    const ushort_t* __restrict__ vbf, const ushort_t* __restrict__ Wqb,
    const ushort_t* __restrict__ Wkb, const ushort_t* __restrict__ Wvb,
    const float* __restrict__ bq, const float* __restrict__ bk,
    const float* __restrict__ bv, ushort_t* __restrict__ qhb,
    ushort_t* __restrict__ khb, ushort_t* __restrict__ vT) {
  __shared__ ushort_t As[2][128 * 32];
  __shared__ ushort_t Bs[2][128 * 32];
  const int t = threadIdx.x;
  const int lane = t & 63;
  const int w = t >> 6;
  const int wr = w >> 1, wc = w & 1;
  const int bid = blockIdx.x;
  const int xcd = bid & 7;
  const int idx = bid >> 3;            // 0..95
  const int which = idx >> 5;          // 0..2
  const int sub = idx & 31;
  const int mt = xcd * 4 + (sub >> 3); // XCD owns 4 contiguous mt blocks
  const int nt = sub & 7;
  const ushort_t* A  = which == 0 ? qbf : which == 1 ? kbf : vbf;
  const ushort_t* Bw = which == 0 ? Wqb : which == 1 ? Wkb : Wvb;
  const float* bias  = which == 0 ? bq  : which == 1 ? bk  : bv;
  const int m0 = mt * 128, n0 = nt * 128;
  const int r16 = lane & 15, kb = lane >> 4;

  f32x4 acc[4][4];
#pragma unroll
  for (int mi = 0; mi < 4; ++mi)
#pragma unroll
    for (int ni = 0; ni < 4; ++ni) acc[mi][ni] = (f32x4){0.f, 0.f, 0.f, 0.f};

  auto STAGE = [&](int buf, int k0) {
#pragma unroll
    for (int i = 0; i < 2; ++i) {
      int c = i * 256 + t;
      int row = c >> 2, kc = (c & 3) * 8;
      gl_lds16(&A[(size_t)(m0 + row) * 1024 + k0 + kc], &As[buf][c * 8]);
      gl_lds16(&Bw[(size_t)(n0 + row) * 1024 + k0 + kc], &Bs[buf][c * 8]);
    }
  };

  STAGE(0, 0);
  __syncthreads();
  int cur = 0;
  for (int kt = 0; kt < 32; ++kt) {
    if (kt + 1 < 32) STAGE(cur ^ 1, (kt + 1) * 32);
    short8 af[4], bf[4];
#pragma unroll
    for (int mi = 0; mi < 4; ++mi)
      af[mi] = *(const short8*)&As[cur][(wr * 64 + mi * 16 + r16) * 32 + kb * 8];
#pragma unroll
    for (int ni = 0; ni < 4; ++ni)
      bf[ni] = *(const short8*)&Bs[cur][(wc * 64 + ni * 16 + r16) * 32 + kb * 8];
#pragma unroll
    for (int mi = 0; mi < 4; ++mi)
#pragma unroll
      for (int ni = 0; ni < 4; ++ni)
        acc[mi][ni] = __builtin_amdgcn_mfma_f32_16x16x32_bf16(af[mi], bf[ni], acc[mi][ni], 0, 0, 0);
    __syncthreads();
    cur ^= 1;
  }

  const int rowD = (lane >> 4) * 4;
#pragma unroll
  for (int mi = 0; mi < 4; ++mi) {
#pragma unroll
    for (int ni = 0; ni < 4; ++ni) {
      int n = n0 + wc * 64 + ni * 16 + (lane & 15);
      float bv4 = bias[n];
      int mbase = m0 + wr * 64 + mi * 16 + rowD;
      float vals[4];
#pragma unroll
      for (int j = 0; j < 4; ++j) vals[j] = acc[mi][ni][j] + bv4;
      int hh = n >> 6, d = n & 63;
      if (which == 0) {
#pragma unroll
        for (int j = 0; j < 4; ++j) {
          int m = mbase + j;
          int b = m >> 9, l = m & 511;
          qhb[(((size_t)(b * 16 + hh)) * 512 + l) * 64 + d] = f2bf(vals[j]);
        }
      } else if (which == 1) {
#pragma unroll
        for (int j = 0; j < 4; ++j) {
          int m = mbase + j;
          int b = m >> 9, r = m & 511;
          khb[(((size_t)(b * 16 + hh)) * 512 + r) * 64 + d] = f2bf(vals[j]);
        }
      } else {
        int b = mbase >> 9, r = mbase & 511;
        u16x4 pkv;
        pkv.x = f2bf(vals[0]); pkv.y = f2bf(vals[1]);
        pkv.z = f2bf(vals[2]); pkv.w = f2bf(vals[3]);
        *(u16x4*)&vT[(((size_t)(b * 16 + hh)) * 64 + d) * 512 + r] = pkv;
      }
    }
  }
}

// ---------------- final O-projection GEMM (K=3072 split, XCD-pinned) ---------
// 256 wgs: xcd = bid&7; idx = bid>>3 (0..31): mt = xcd*4 + (idx>>3), nt = idx&7.
// Per XCD: A rows 4x768KB = 3MB + B 6.3MB -> mostly L2-resident.
__global__ __launch_bounds__(256) void gemm_out(const ushort_t* __restrict__ A,
                                                const ushort_t* __restrict__ Bw,
                                                const float* __restrict__ bias,
                                                float* __restrict__ Cout) {
  __shared__ ushort_t As[2][128 * 32];
  __shared__ ushort_t Bs[2][128 * 32];
  const int t = threadIdx.x;
  const int lane = t & 63;
  const int w = t >> 6;
  const int wr = w >> 1, wc = w & 1;
  const int bid = blockIdx.x;
  const int xcd = bid & 7;
  const int idx = bid >> 3;
  const int mt = xcd * 4 + (idx >> 3);
  const int nt = idx & 7;
  const int m0 = mt * 128, n0 = nt * 128;
  const int r16 = lane & 15, kb = lane >> 4;

  f32x4 acc[4][4];
#pragma unroll
  for (int mi = 0; mi < 4; ++mi)
#pragma unroll
    for (int ni = 0; ni < 4; ++ni) acc[mi][ni] = (f32x4){0.f, 0.f, 0.f, 0.f};

  auto STAGE = [&](int buf, int k0) {
#pragma unroll
    for (int i = 0; i < 2; ++i) {
      int c = i * 256 + t;
      int row = c >> 2, kc = (c & 3) * 8;
      gl_lds16(&A[(size_t)(m0 + row) * 3072 + k0 + kc], &As[buf][c * 8]);
      gl_lds16(&Bw[(size_t)(n0 + row) * 3072 + k0 + kc], &Bs[buf][c * 8]);
    }
  };

  STAGE(0, 0);
  __syncthreads();
  int cur = 0;
  for (int kt = 0; kt < 96; ++kt) {
    if (kt + 1 < 96) STAGE(cur ^ 1, (kt + 1) * 32);
    short8 af[4], bf[4];
#pragma unroll
    for (int mi = 0; mi < 4; ++mi)
      af[mi] = *(const short8*)&As[cur][(wr * 64 + mi * 16 + r16) * 32 + kb * 8];
#pragma unroll
    for (int ni = 0; ni < 4; ++ni)
      bf[ni] = *(const short8*)&Bs[cur][(wc * 64 + ni * 16 + r16) * 32 + kb * 8];
#pragma unroll
    for (int mi = 0; mi < 4; ++mi)
#pragma unroll
      for (int ni = 0; ni < 4; ++ni)
        acc[mi][ni] = __builtin_amdgcn_mfma_f32_16x16x32_bf16(af[mi], bf[ni], acc[mi][ni], 0, 0, 0);
    __syncthreads();
    cur ^= 1;
  }

  const int rowD = (lane >> 4) * 4;
#pragma unroll
  for (int mi = 0; mi < 4; ++mi) {
#pragma unroll
    for (int ni = 0; ni < 4; ++ni) {
      int n = n0 + wc * 64 + ni * 16 + (lane & 15);
      float bv = bias[n];
      int mbase = m0 + wr * 64 + mi * 16 + rowD;
#pragma unroll
      for (int j = 0; j < 4; ++j)
        Cout[(size_t)(mbase + j) * 1024 + n] = acc[mi][ni][j] + bv;
    }
  }
}

// ---------------- fused attention, full MFMA (round-6 structure) ----------------
// grid: 512 wgs. slot=bid&7 -> XCD; grp=bid>>3: h = slot*2 + (grp&1), l0=(grp>>1)*16.
__global__ __launch_bounds__(256, 2) void attn_mfma(
    const ushort_t* __restrict__ qhb, const ushort_t* __restrict__ khb,
    const ushort_t* __restrict__ vT, const float* __restrict__ rel,
    const int* __restrict__ mask, ushort_t* __restrict__ Abig) {
  __shared__ ushort_t qs[8][16][64];          // bf16 q [b][l][8 blocks of 8, swizzled]
  __shared__ float sp2[2][8][17][20];         // rel scores [buf][b][l(+1 pad)][r(+pad)]
  const int t = threadIdx.x;
  const int w = t >> 6, lane = t & 63, lh = lane & 15, lg = lane >> 4;
  const int bid = blockIdx.x;
  const int slot = bid & 7, grp = bid >> 3;
  const int h = slot * 2 + (grp & 1);         // heads {2s,2s+1} pinned to XCD s
  const int l0 = (grp >> 1) * 16;
  const int b0 = w * 2;

  // ---- stage q (bf16) into swizzled qs ----
  {
    int idx = t * 32;
    int b = idx >> 10, l = (idx >> 6) & 15, d0 = idx & 63;   // d0 in {0,32}
    const ushort_t* src = &qhb[(((size_t)(b * 16 + h)) * 512 + l0 + l) * 64 + d0];
    int xr = (l & 7) ^ b;
#pragma unroll
    for (int jj = 0; jj < 4; ++jj) {
      short8 vq = *(const short8*)&src[jj * 8];
      int pos = ((d0 >> 3) + jj) ^ xr;
      *(short8*)&qs[b][l][pos * 8] = vq;
    }
  }

  f32x4 R[16];
  const float* relbase = &rel[(size_t)(l0 + w * 4) * 512 * 1024 + h * 64 + lg * 8];
  auto LOAD_REL = [&](int r0_) {
#pragma unroll
    for (int li = 0; li < 4; ++li) {
      const float* rp = relbase + ((size_t)li * 512 + r0_ + lh) * 1024;
#pragma unroll
      for (int kb = 0; kb < 2; ++kb) {
        R[li * 4 + kb * 2 + 0] = *(const f32x4*)&rp[kb * 32];
        R[li * 4 + kb * 2 + 1] = *(const f32x4*)&rp[kb * 32 + 4];
      }
    }
  };
  LOAD_REL(0);

  f32x4 O[2][4];                              // [b-hat][d-tile], rows d=4lg+j, col l=lh
#pragma unroll
  for (int i = 0; i < 2; ++i)
#pragma unroll
    for (int j = 0; j < 4; ++j) O[i][j] = (f32x4){0.f, 0.f, 0.f, 0.f};
  float m_run[2] = {-1e30f, -1e30f}, s_run[2] = {0.f, 0.f};

  __syncthreads();

#pragma unroll 1
  for (int it = 0; it < 32; ++it) {
    const int r0 = it * 16;
    const int cur = it & 1;

    // K / V / mask loads for this tile (consumed in phase 2)
    short8 kf[2][2], vf[2][4];
#pragma unroll
    for (int bh = 0; bh < 2; ++bh) {
#pragma unroll
      for (int kb = 0; kb < 2; ++kb)
        kf[bh][kb] = *(const short8*)&khb[(((size_t)((b0 + bh) * 16 + h)) * 512 + r0 + lh) * 64 + kb * 32 + lg * 8];
#pragma unroll
      for (int dt = 0; dt < 4; ++dt)
        vf[bh][dt] = *(const short8*)&vT[(((size_t)((b0 + bh) * 16 + h)) * 64 + dt * 16 + lh) * 512 + r0 + lg * 8];
    }
    int4 mk = *(const int4*)&mask[(size_t)(l0 + lh) * 512 + r0 + lg * 4];

    // ---- phase 1: rel-term MFMA (consumes R) -> sp2[cur] ----
#pragma unroll
    for (int li = 0; li < 4; ++li) {
      frag_u a0, a1;
      f32x4 v00 = R[li * 4 + 0], v01 = R[li * 4 + 1];
      f32x4 v10 = R[li * 4 + 2], v11 = R[li * 4 + 3];
      a0.w[0] = pk_bf16(v00[0], v00[1]); a0.w[1] = pk_bf16(v00[2], v00[3]);
      a0.w[2] = pk_bf16(v01[0], v01[1]); a0.w[3] = pk_bf16(v01[2], v01[3]);
      a1.w[0] = pk_bf16(v10[0], v10[1]); a1.w[1] = pk_bf16(v10[2], v10[3]);
      a1.w[2] = pk_bf16(v11[0], v11[1]); a1.w[3] = pk_bf16(v11[2], v11[3]);
      int l = w * 4 + li;
      int xr2 = (l & 7) ^ (lh & 7);
      short8 q0 = *(const short8*)&qs[lh & 7][l][(lg ^ xr2) * 8];
      short8 q1 = *(const short8*)&qs[lh & 7][l][((4 + lg) ^ xr2) * 8];
      f32x4 acc = (f32x4){0.f, 0.f, 0.f, 0.f};
      acc = __builtin_amdgcn_mfma_f32_16x16x32_bf16(a0.s, q0, acc, 0, 0, 0);
      acc = __builtin_amdgcn_mfma_f32_16x16x32_bf16(a1.s, q1, acc, 0, 0, 0);
      if (lh < 8) *(f32x4*)&sp2[cur][lh][l][lg * 4] = acc;
    }
    // issue next rel tile (R dead after cvt above)
    if (it < 31) LOAD_REL(r0 + 16);

    __syncthreads();

    // ---- phase 2: QK + softmax + PV ----
    __builtin_amdgcn_s_setprio(1);
#pragma unroll
    for (int bh = 0; bh < 2; ++bh) {
      int xqk = (lh & 7) ^ (b0 + bh);
      short8 qb0 = *(const short8*)&qs[b0 + bh][lh][(lg ^ xqk) * 8];
      short8 qb1 = *(const short8*)&qs[b0 + bh][lh][((4 + lg) ^ xqk) * 8];
      f32x4 s1 = (f32x4){0.f, 0.f, 0.f, 0.f};
      s1 = __builtin_amdgcn_mfma_f32_16x16x32_bf16(kf[bh][0], qb0, s1, 0, 0, 0);
      s1 = __builtin_amdgcn_mfma_f32_16x16x32_bf16(kf[bh][1], qb1, s1, 0, 0, 0);
      f32x4 s2 = *(const f32x4*)&sp2[cur][b0 + bh][lh][lg * 4];
      f32x4 S;
      S[0] = (mk.x == 0) ? -1e9f : (s1[0] * 0.125f + s2[0]);
      S[1] = (mk.y == 0) ? -1e9f : (s1[1] * 0.125f + s2[1]);
      S[2] = (mk.z == 0) ? -1e9f : (s1[2] * 0.125f + s2[2]);
      S[3] = (mk.w == 0) ? -1e9f : (s1[3] * 0.125f + s2[3]);
      float mt = fmaxf(fmaxf(S[0], S[1]), fmaxf(S[2], S[3]));
      mt = fmaxf(mt, __shfl_xor(mt, 16));
      mt = fmaxf(mt, __shfl_xor(mt, 32));
      float mn = fmaxf(m_run[bh], mt);
      float fsc = __expf(m_run[bh] - mn);
      f32x4 P;
      P[0] = __expf(S[0] - mn); P[1] = __expf(S[1] - mn);
      P[2] = __expf(S[2] - mn); P[3] = __expf(S[3] - mn);
      float ps = P[0] + P[1] + P[2] + P[3];
      ps += __shfl_xor(ps, 16);
      ps += __shfl_xor(ps, 32);
      s_run[bh] = s_run[bh] * fsc + ps;
      m_run[bh] = mn;
#pragma unroll
      for (int dt = 0; dt < 4; ++dt) O[bh][dt] *= fsc;
      u32 pk0 = pk_bf16(P[0], P[1]), pk1 = pk_bf16(P[2], P[3]);
      int s0l = (lh + 32 * lg) & 63;
      u32 w0 = (u32)__shfl((int)pk0, s0l), w1 = (u32)__shfl((int)pk1, s0l);
      u32 w2 = (u32)__shfl((int)pk0, s0l + 16), w3 = (u32)__shfl((int)pk1, s0l + 16);
      bool vld = (lg < 2);
      frag_u pb;
      pb.w[0] = vld ? w0 : 0u; pb.w[1] = vld ? w1 : 0u;
      pb.w[2] = vld ? w2 : 0u; pb.w[3] = vld ? w3 : 0u;
#pragma unroll
      for (int dt = 0; dt < 4; ++dt)
        O[bh][dt] = __builtin_amdgcn_mfma_f32_16x16x32_bf16(vf[bh][dt], pb.s, O[bh][dt], 0, 0, 0);
    }
    __builtin_amdgcn_s_setprio(0);
  }

  // ---- epilogue: O /= s; hi/lo/hi bf16 split into Abig [b*512+l][3072] ----
#pragma unroll
  for (int bh = 0; bh < 2; ++bh) {
    float inv = 1.0f / s_run[bh];
    ushort_t* rowp = &Abig[(size_t)((b0 + bh) * 512 + l0 + lh) * 3072];
#pragma unroll
    for (int dt = 0; dt < 4; ++dt) {
      int c = h * 64 + dt * 16 + lg * 4;
      f32x4 o = O[bh][dt];
      float x0 = o[0] * inv, x1 = o[1] * inv, x2 = o[2] * inv, x3 = o[3] * inv;
      u16x4 hi, lo;
      hi.x = f2bf(x0); lo.x = f2bf(x0 - bf2f(hi.x));
      hi.y = f2bf(x1); lo.y = f2bf(x1 - bf2f(hi.y));
      hi.z = f2bf(x2); lo.z = f2bf(x2 - bf2f(hi.z));
      hi.w = f2bf(x3); lo.w = f2bf(x3 - bf2f(hi.w));
      *(u16x4*)&rowp[c] = hi;
      *(u16x4*)&rowp[1024 + c] = lo;
      *(u16x4*)&rowp[2048 + c] = hi;
    }
  }
}

// ---------------- launcher ----------------
extern "C" void kernel_launch(void* const* d_in, const int* in_sizes, int n_in,
                              void* d_out, int out_size, void* d_ws, size_t ws_size,
                              hipStream_t stream) {
  const float* q    = (const float*)d_in[0];
  const float* k    = (const float*)d_in[1];
  const float* v    = (const float*)d_in[2];
  const float* rel  = (const float*)d_in[3];
  const int*   mask = (const int*)d_in[4];
  const float* Wq   = (const float*)d_in[5];
  const float* bq   = (const float*)d_in[6];
  const float* Wk   = (const float*)d_in[7];
  const float* bk   = (const float*)d_in[8];
  const float* Wv   = (const float*)d_in[9];
  const float* bv   = (const float*)d_in[10];
  const float* Wo   = (const float*)d_in[11];
  const float* bo   = (const float*)d_in[12];
  float* out = (float*)d_out;

  char* ws = (char*)d_ws;
  ushort_t* qhb = (ushort_t*)(ws);                       // 8.39 MB bf16 [b][h][l][d]
  ushort_t* khb = (ushort_t*)(ws + 16777216);            // 8.39 MB bf16 [b][h][r][d]
  ushort_t* vT  = (ushort_t*)(ws + 16777216 + 8388608);  // 8.39 MB bf16 [b][h][d][r]
  ushort_t* X   = (ushort_t*)(ws + 33554432);            // 25.17 MB: qbf/kbf/vbf then Abig
  ushort_t* Y   = (ushort_t*)(ws + 58720256);            // 6.29 MB: W*bf then Wo split
  ushort_t* qbf = X;
  ushort_t* kbf = X + 4194304;
  ushort_t* vbf = X + 8388608;
  ushort_t* Wqb = Y;
  ushort_t* Wkb = Y + 1048576;
  ushort_t* Wvb = Y + 2097152;

  to_bf16_3<<<1536, 256, 0, stream>>>(q, k, v, X, 20, 3145728);
  to_bf16_3<<<384, 256, 0, stream>>>(Wq, Wk, Wv, Y, 18, 786432);

  gemm_qkv<<<768, 256, 0, stream>>>(qbf, kbf, vbf, Wqb, Wkb, Wvb,
                                    bq, bk, bv, qhb, khb, vT);

  split3_bf16<<<1024, 256, 0, stream>>>(Wo, Y, 1048576);

  attn_mfma<<<512, 256, 0, stream>>>(qhb, khb, vT, rel, mask, X);

  gemm_out<<<256, 256, 0, stream>>>(X, Y, bo, out);
}